// Round 2
// baseline (32512.918 us; speedup 1.0000x reference)
//
#include <hip/hip_runtime.h>
#include <hip/hip_bf16.h>

#define NP 63   // number of patches

__device__ __forceinline__ float sigf(float x){ return 1.0f/(1.0f+expf(-x)); }

// ---------------- RevIN stats: mean/std per (b,d,m) series of 512 ----------------
__global__ void __launch_bounds__(256) k_revin(const float* __restrict__ series,
    float* __restrict__ meanv, float* __restrict__ stdv)
{
  int n = blockIdx.x, tid = threadIdx.x;
  __shared__ float s1[256], s2[256];
  const float* p = series + n*512;
  float a = 0.f, b = 0.f;
  for(int t=tid;t<512;t+=256){ float v=p[t]; a+=v; b+=v*v; }
  s1[tid]=a; s2[tid]=b; __syncthreads();
  for(int s=128;s>0;s>>=1){
    if(tid<s){ s1[tid]+=s1[tid+s]; s2[tid]+=s2[tid+s]; }
    __syncthreads();
  }
  if(tid==0){
    float mu = s1[0]*(1.f/512.f);
    float var = fmaxf(s2[0]*(1.f/512.f) - mu*mu, 0.f);
    meanv[n]=mu; stdv[n]=sqrtf(var+1e-5f);
  }
}

// ---------------- patch embed: x[n,p,h] = sum_i normed[n,p*8+i]*up_w[i,h] ----------------
__global__ void __launch_bounds__(256) k_patch(const float* __restrict__ series,
    const float* __restrict__ rs, const float* __restrict__ rb,
    const float* __restrict__ up_w, const float* __restrict__ meanv,
    const float* __restrict__ stdv, float* __restrict__ x)
{
  int n = blockIdx.x, tid = threadIdx.x;
  int m = n & 7;
  __shared__ float sn[512];
  float mu = meanv[n], sd = stdv[n];
  float sc = rs[m], bi = rb[m];
  float A = sc/sd, C = bi - mu*A;
  const float* p = series + n*512;
  for(int t=tid;t<512;t+=256) sn[t] = p[t]*A + C;
  __syncthreads();
  float w[16];
  #pragma unroll
  for(int i=0;i<16;i++) w[i] = up_w[i*256+tid];
  float* xo = x + n*(NP*256);
  for(int pi=0;pi<NP;pi++){
    float acc=0.f;
    #pragma unroll
    for(int i=0;i<16;i++) acc = fmaf(sn[pi*8+i], w[i], acc);
    xo[pi*256+tid] = acc;
  }
}

// ---------------- W_od = wo @ down_w  (512x512)@(512x256) per block ----------------
__global__ void __launch_bounds__(256) k_wod(const float* __restrict__ wo,
    const float* __restrict__ dw, float* __restrict__ wod)
{
  int i = blockIdx.x, blk = blockIdx.y, tid = threadIdx.x;
  __shared__ float row[512];
  const float* wr = wo + (blk*512 + i)*512;
  for(int k=tid;k<512;k+=256) row[k]=wr[k];
  __syncthreads();
  const float* d = dw + blk*512*256;
  float acc=0.f;
  for(int k=0;k<512;k++) acc = fmaf(row[k], d[k*256+tid], acc);
  wod[(blk*512+i)*256+tid]=acc;
}

// ---------------- LSTM step: z = x_t@wi + h_{t-1}@wh + b, gates, write h_t into hs ----------------
// grid (16 n-tiles, 16 jj-tiles), 256 thr. Tile 64n x 32jj x 4 gates. h read from hs[t-1] (race-free).
__global__ void __launch_bounds__(256) k_lstm(const float* __restrict__ x,
    float* __restrict__ cst, float* __restrict__ hs,
    const float* __restrict__ wi, const float* __restrict__ wh,
    const float* __restrict__ bias, int t)
{
  __shared__ float As[64][20];   // [n][k]  (16-k chunk)
  __shared__ float Bs[128][20];  // [g*32+tj][k]
  int tid = threadIdx.x;
  int n0 = blockIdx.x*64, jj0 = blockIdx.y*32;
  int tj = tid&31, tn = tid>>5;       // compute mapping
  int kk = tid&15, nl = tid>>4;       // A staging
  int jl = tid&127, kh = tid>>7;      // B staging
  int colB = jj0 + (jl&31) + 512*(jl>>5);
  float acc[4][8];
  #pragma unroll
  for(int g=0;g<4;g++){
    #pragma unroll
    for(int a=0;a<8;a++) acc[g][a]=0.f;
  }
  const int K = (t==0)?256:768;
  int tp = (t>0)? (t-1) : 0;
  const float* arow[4]; const float* hrow[4];
  #pragma unroll
  for(int i=0;i<4;i++){
    int n = n0 + nl + 16*i;
    arow[i] = x + (n*NP + t)*256;
    hrow[i] = hs + (n*NP + tp)*512;
  }
  for(int k0=0;k0<K;k0+=16){
    int k = k0 + kk;
    if(k0 < 256){
      #pragma unroll
      for(int i=0;i<4;i++) As[nl+16*i][kk] = arow[i][k];
    } else {
      #pragma unroll
      for(int i=0;i<4;i++) As[nl+16*i][kk] = hrow[i][k-256];
    }
    float tmpB[8];
    if(k0 < 256){
      #pragma unroll
      for(int i=0;i<8;i++) tmpB[i] = wi[(k0+kh*8+i)*2048 + colB];
    } else {
      #pragma unroll
      for(int i=0;i<8;i++) tmpB[i] = wh[(k0-256+kh*8+i)*2048 + colB];
    }
    #pragma unroll
    for(int i=0;i<8;i++) Bs[jl][kh*8+i] = tmpB[i];
    __syncthreads();
    #pragma unroll
    for(int k4=0;k4<4;k4++){
      float av[8][4], bv[4][4];
      #pragma unroll
      for(int a=0;a<8;a++){
        #pragma unroll
        for(int q=0;q<4;q++) av[a][q] = As[tn*8+a][k4*4+q];
      }
      #pragma unroll
      for(int g=0;g<4;g++){
        #pragma unroll
        for(int q=0;q<4;q++) bv[g][q] = Bs[g*32+tj][k4*4+q];
      }
      #pragma unroll
      for(int g=0;g<4;g++){
        #pragma unroll
        for(int a=0;a<8;a++){
          #pragma unroll
          for(int q=0;q<4;q++) acc[g][a] = fmaf(av[a][q], bv[g][q], acc[g][a]);
        }
      }
    }
    __syncthreads();
  }
  int jj = jj0 + tj;
  float bI=bias[jj], bF=bias[jj+512], bG=bias[jj+1024], bO=bias[jj+1536];
  #pragma unroll
  for(int a=0;a<8;a++){
    int n = n0 + tn*8 + a;
    float zi=acc[0][a]+bI, zf=acc[1][a]+bF, zg=acc[2][a]+bG, zo=acc[3][a]+bO;
    float cold = (t==0)?0.f:cst[n*512+jj];
    float c = sigf(zf)*cold + sigf(zi)*tanhf(zg);
    float hv = sigf(zo)*tanhf(c);
    cst[n*512+jj]=c;
    hs[(n*NP+t)*512+jj]=hv;
  }
}

// ---------------- rms_inv over H2=512 for every attention row (b,m,p,d) ----------------
__global__ void __launch_bounds__(256) k_rms(const float* __restrict__ hs, float* __restrict__ rmsi)
{
  int tid = threadIdx.x;
  int r = blockIdx.x*4 + (tid>>6);
  int lane = tid&63;
  int bq = r/8064; int rr = r - bq*8064;
  int m = rr/1008; int rem = rr - m*1008;
  int p = rem>>4; int d = rem&15;
  int n = (bq*16+d)*8+m;
  const float* hp = hs + (n*NP+p)*512;
  float s=0.f;
  for(int c=lane;c<512;c+=64){ float v=hp[c]; s += v*v; }
  #pragma unroll
  for(int off=32;off>0;off>>=1) s += __shfl_down(s,off);
  if(lane==0) rmsi[r] = rsqrtf(s*(1.f/512.f)+1e-6f);
}

// ---------------- qkv GEMM: A = rmsnorm(hs) (8064x512), B = [wq|wk|wv] (512x768) ----------------
// grid (126, 6), tile 64r x 128c, per-thread 4x8, k-block 4.
__global__ void __launch_bounds__(256) k_qkv(const float* __restrict__ hs,
    const float* __restrict__ rmsi, const float* __restrict__ ns,
    const float* __restrict__ wq, const float* __restrict__ wk,
    const float* __restrict__ wv, float* __restrict__ qkv, int cb)
{
  __shared__ float As[64][20];
  __shared__ float Bs[128][20];
  int tid = threadIdx.x;
  int r0 = blockIdx.x*64, c0 = blockIdx.y*128;
  const float* Bp; int bw, cbase;
  if(c0 < 512){ Bp=wq; bw=512; cbase=0; }
  else if(c0 == 512){ Bp=wk; bw=128; cbase=512; }
  else { Bp=wv; bw=128; cbase=640; }
  int kk=tid&15, rl=tid>>4;
  int cl=tid&127, kh=tid>>7;
  int cB = c0 + cl - cbase;
  const float* ap[4]; float rv[4];
  #pragma unroll
  for(int i=0;i<4;i++){
    int r = r0 + rl + 16*i;
    int m = r/1008; int rem = r - m*1008; int p = rem>>4; int d = rem&15;
    int n = (cb*16+d)*8+m;
    ap[i] = hs + (n*NP+p)*512;
    rv[i] = rmsi[cb*8064 + r];
  }
  int tc=tid&15, tr=tid>>4;
  float acc[4][8];
  #pragma unroll
  for(int a=0;a<4;a++){
    #pragma unroll
    for(int b_=0;b_<8;b_++) acc[a][b_]=0.f;
  }
  for(int k0=0;k0<512;k0+=16){
    float nsv = ns[k0+kk];
    #pragma unroll
    for(int i=0;i<4;i++) As[rl+16*i][kk] = ap[i][k0+kk]*rv[i]*nsv;
    float tmpB[8];
    #pragma unroll
    for(int i=0;i<8;i++) tmpB[i] = Bp[(k0+kh*8+i)*bw + cB];
    #pragma unroll
    for(int i=0;i<8;i++) Bs[cl][kh*8+i] = tmpB[i];
    __syncthreads();
    #pragma unroll
    for(int k4=0;k4<4;k4++){
      float av[4][4], bv[8][4];
      #pragma unroll
      for(int a=0;a<4;a++){
        #pragma unroll
        for(int q=0;q<4;q++) av[a][q] = As[tr+16*a][k4*4+q];
      }
      #pragma unroll
      for(int b_=0;b_<8;b_++){
        #pragma unroll
        for(int q=0;q<4;q++) bv[b_][q] = Bs[tc+16*b_][k4*4+q];
      }
      #pragma unroll
      for(int a=0;a<4;a++){
        #pragma unroll
        for(int b_=0;b_<8;b_++){
          #pragma unroll
          for(int q=0;q<4;q++) acc[a][b_] = fmaf(av[a][q], bv[b_][q], acc[a][b_]);
        }
      }
    }
    __syncthreads();
  }
  #pragma unroll
  for(int a=0;a<4;a++){
    int r = r0+tr+16*a;
    #pragma unroll
    for(int b_=0;b_<8;b_++) qkv[r*768 + c0+tc+16*b_] = acc[a][b_];
  }
}

// ---------------- attention: per (m*63+p, head): S=16 (=d), hd=64, GQA 8q/2kv ----------------
__global__ void __launch_bounds__(256) k_attn(float* __restrict__ qkv)
{
  int r3 = blockIdx.x, h = blockIdx.y;
  int tid = threadIdx.x;
  __shared__ float qs[16][64];
  __shared__ float ks[16][65];
  __shared__ float vs[16][64];
  __shared__ float P[16][17];
  float* base = qkv + r3*16*768;
  int xx = tid&63, s4 = tid>>6;
  int kvh = (h>>2)*64;
  #pragma unroll
  for(int a=0;a<4;a++){
    int s = s4 + 4*a;
    qs[s][xx] = base[s*768 + h*64 + xx];
    ks[s][xx] = base[s*768 + 512 + kvh + xx];
    vs[s][xx] = base[s*768 + 640 + kvh + xx];
  }
  __syncthreads();
  int i = tid>>4, j = tid&15;
  float sc = 0.f;
  #pragma unroll
  for(int x=0;x<64;x++) sc = fmaf(qs[i][x], ks[j][x], sc);
  P[i][j] = sc*0.125f;
  __syncthreads();
  float row[16];
  #pragma unroll
  for(int jj=0;jj<16;jj++) row[jj] = P[i][jj];
  float mx = row[0];
  #pragma unroll
  for(int jj=1;jj<16;jj++) mx = fmaxf(mx, row[jj]);
  float sum = 0.f;
  #pragma unroll
  for(int jj=0;jj<16;jj++) sum += expf(row[jj]-mx);
  float pme = expf(row[j]-mx)/sum;
  __syncthreads();
  P[i][j] = pme;
  __syncthreads();
  #pragma unroll
  for(int a=0;a<4;a++){
    int s = s4 + 4*a;
    float o = 0.f;
    #pragma unroll
    for(int jj=0;jj<16;jj++) o = fmaf(P[s][jj], vs[jj][xx], o);
    base[s*768 + h*64 + xx] = o;   // overwrite q region with attention output
  }
}

// ---------------- bel GEMM: O (8064x512, in q region) @ W_od (512x256) -> scatter to x ----------------
__global__ void __launch_bounds__(256) k_bel(const float* __restrict__ qkv,
    const float* __restrict__ wod, float* __restrict__ x, int cb)
{
  __shared__ float As[64][20];
  __shared__ float Bs[128][20];
  int tid = threadIdx.x;
  int r0 = blockIdx.x*64, c0 = blockIdx.y*128;
  int kk=tid&15, rl=tid>>4;
  int cl=tid&127, kh=tid>>7;
  int tc=tid&15, tr=tid>>4;
  float acc[4][8];
  #pragma unroll
  for(int a=0;a<4;a++){
    #pragma unroll
    for(int b_=0;b_<8;b_++) acc[a][b_]=0.f;
  }
  for(int k0=0;k0<512;k0+=16){
    #pragma unroll
    for(int i=0;i<4;i++){
      int r = r0+rl+16*i;
      As[rl+16*i][kk] = qkv[r*768 + k0+kk];
    }
    float tmpB[8];
    #pragma unroll
    for(int i=0;i<8;i++) tmpB[i] = wod[(k0+kh*8+i)*256 + c0+cl];
    #pragma unroll
    for(int i=0;i<8;i++) Bs[cl][kh*8+i] = tmpB[i];
    __syncthreads();
    #pragma unroll
    for(int k4=0;k4<4;k4++){
      float av[4][4], bv[8][4];
      #pragma unroll
      for(int a=0;a<4;a++){
        #pragma unroll
        for(int q=0;q<4;q++) av[a][q] = As[tr+16*a][k4*4+q];
      }
      #pragma unroll
      for(int b_=0;b_<8;b_++){
        #pragma unroll
        for(int q=0;q<4;q++) bv[b_][q] = Bs[tc+16*b_][k4*4+q];
      }
      #pragma unroll
      for(int a=0;a<4;a++){
        #pragma unroll
        for(int b_=0;b_<8;b_++){
          #pragma unroll
          for(int q=0;q<4;q++) acc[a][b_] = fmaf(av[a][q], bv[b_][q], acc[a][b_]);
        }
      }
    }
    __syncthreads();
  }
  #pragma unroll
  for(int a=0;a<4;a++){
    int r = r0+tr+16*a;
    int m = r/1008; int rem = r - m*1008; int p = rem>>4; int d = rem&15;
    int n = (cb*16+d)*8+m;
    float* xo = x + (n*NP+p)*256;
    #pragma unroll
    for(int b_=0;b_<8;b_++) xo[c0+tc+16*b_] = acc[a][b_];
  }
}

// ---------------- head: rmsnorm(last patch) @ [point_w|quant_w], denorm, write f32 ----------------
__global__ void __launch_bounds__(256) k_head(const float* __restrict__ x,
    const float* __restrict__ meanv, const float* __restrict__ stdv,
    const float* __restrict__ rs, const float* __restrict__ rb,
    const float* __restrict__ hns, const float* __restrict__ pw,
    const float* __restrict__ qw, float* __restrict__ out)
{
  int n = blockIdx.x, tid = threadIdx.x;
  __shared__ float nb[256];
  __shared__ float red[256];
  float v = x[(n*NP + 62)*256 + tid];
  red[tid] = v*v; __syncthreads();
  for(int s=128;s>0;s>>=1){
    if(tid<s) red[tid]+=red[tid+s];
    __syncthreads();
  }
  float rinv = rsqrtf(red[0]*(1.f/256.f)+1e-6f);
  nb[tid] = v*rinv*hns[tid];
  __syncthreads();
  int m = n&7;
  float mu=meanv[n], sd=stdv[n], sc=rs[m], bi=rb[m];
  for(int col=tid; col<384; col+=256){
    float acc=0.f;
    int slot, hh;
    if(col < 96){
      for(int k=0;k<256;k++) acc = fmaf(nb[k], pw[k*96+col], acc);
      slot = 0; hh = col;
    } else {
      int cq = col-96;
      for(int k=0;k<256;k++) acc = fmaf(nb[k], qw[k*288+cq], acc);
      int qi = cq - (cq/3)*3;
      slot = 1 + qi; hh = cq/3;
    }
    float y = (acc - bi)/sc*sd + mu;
    out[(slot*1024 + n)*96 + hh] = y;
  }
}

extern "C" void kernel_launch(void* const* d_in, const int* in_sizes, int n_in,
                              void* d_out, int out_size, void* d_ws, size_t ws_size,
                              hipStream_t stream)
{
  const float* series    = (const float*)d_in[0];
  const float* rs        = (const float*)d_in[1];
  const float* rb        = (const float*)d_in[2];
  const float* up_w      = (const float*)d_in[3];
  const float* lstm_wi   = (const float*)d_in[4];
  const float* lstm_wh   = (const float*)d_in[5];
  const float* lstm_b    = (const float*)d_in[6];
  const float* norm_scale= (const float*)d_in[7];
  const float* wq        = (const float*)d_in[8];
  const float* wk        = (const float*)d_in[9];
  const float* wv        = (const float*)d_in[10];
  const float* wo        = (const float*)d_in[11];
  const float* down_w    = (const float*)d_in[12];
  const float* head_ns   = (const float*)d_in[13];
  const float* point_w   = (const float*)d_in[14];
  const float* quant_w   = (const float*)d_in[15];
  float* out = (float*)d_out;

  float* ws = (float*)d_ws;
  float* meanv = ws;                    // 1024
  float* stdv  = meanv + 1024;          // 1024
  float* rmsi  = stdv  + 1024;          // 64512
  float* cst   = rmsi  + 64512;         // 1024*512
  float* xbuf  = cst   + 524288;        // 1024*63*256
  float* hsb   = xbuf  + 16515072;      // 1024*63*512
  float* qkvb  = hsb   + 33030144;      // 8064*768
  float* wod   = qkvb  + 6193152;       // 4*512*256
  // total ~56.9M floats (~228 MiB)

  k_revin<<<1024,256,0,stream>>>(series, meanv, stdv);
  k_patch<<<1024,256,0,stream>>>(series, rs, rb, up_w, meanv, stdv, xbuf);
  k_wod<<<dim3(512,4),256,0,stream>>>(wo, down_w, wod);

  for(int blk=0; blk<4; blk++){
    const float* wi = lstm_wi + blk*256*2048;
    const float* wh = lstm_wh + blk*512*2048;
    const float* bb = lstm_b  + blk*2048;
    for(int t=0; t<NP; t++)
      k_lstm<<<dim3(16,16),256,0,stream>>>(xbuf, cst, hsb, wi, wh, bb, t);
    k_rms<<<16128,256,0,stream>>>(hsb, rmsi);
    for(int cb=0; cb<8; cb++){
      k_qkv<<<dim3(126,6),256,0,stream>>>(hsb, rmsi, norm_scale + blk*512,
          wq + blk*512*512, wk + blk*512*128, wv + blk*512*128, qkvb, cb);
      k_attn<<<dim3(504,8),256,0,stream>>>(qkvb);
      k_bel<<<dim3(126,2),256,0,stream>>>(qkvb, wod + blk*512*256, xbuf, cb);
    }
  }
  k_head<<<1024,256,0,stream>>>(xbuf, meanv, stdv, rs, rb, head_ns, point_w, quant_w, out);
}

// Round 3
// 5997.948 us; speedup vs baseline: 5.4207x; 5.4207x over previous
//
#include <hip/hip_runtime.h>
#include <hip/hip_bf16.h>

#define NP 63   // number of patches

typedef __attribute__((ext_vector_type(8))) short short8;
typedef __attribute__((ext_vector_type(4))) float f32x4;

__device__ __forceinline__ float sigf(float x){ return 1.0f/(1.0f+expf(-x)); }
__device__ __forceinline__ float u2f(ushort u){ __hip_bfloat16 h; *(ushort*)&h = u; return __bfloat162float(h); }
__device__ __forceinline__ ushort f2u(float f){ __hip_bfloat16 h = __float2bfloat16(f); return *(ushort*)&h; }

// ---------------- RevIN stats ----------------
__global__ void __launch_bounds__(256) k_revin(const float* __restrict__ series,
    float* __restrict__ meanv, float* __restrict__ stdv)
{
  int n = blockIdx.x, tid = threadIdx.x;
  __shared__ float s1[256], s2[256];
  const float* p = series + n*512;
  float a = 0.f, b = 0.f;
  for(int t=tid;t<512;t+=256){ float v=p[t]; a+=v; b+=v*v; }
  s1[tid]=a; s2[tid]=b; __syncthreads();
  for(int s=128;s>0;s>>=1){
    if(tid<s){ s1[tid]+=s1[tid+s]; s2[tid]+=s2[tid+s]; }
    __syncthreads();
  }
  if(tid==0){
    float mu = s1[0]*(1.f/512.f);
    float var = fmaxf(s2[0]*(1.f/512.f) - mu*mu, 0.f);
    meanv[n]=mu; stdv[n]=sqrtf(var+1e-5f);
  }
}

// ---------------- patch embed -> bf16 xbuf ----------------
__global__ void __launch_bounds__(256) k_patch(const float* __restrict__ series,
    const float* __restrict__ rs, const float* __restrict__ rb,
    const float* __restrict__ up_w, const float* __restrict__ meanv,
    const float* __restrict__ stdv, ushort* __restrict__ x)
{
  int n = blockIdx.x, tid = threadIdx.x;
  int m = n & 7;
  __shared__ float sn[512];
  float mu = meanv[n], sd = stdv[n];
  float A = rs[m]/sd, C = rb[m] - mu*A;
  const float* p = series + n*512;
  for(int t=tid;t<512;t+=256) sn[t] = p[t]*A + C;
  __syncthreads();
  float w[16];
  #pragma unroll
  for(int i=0;i<16;i++) w[i] = up_w[i*256+tid];
  ushort* xo = x + n*(NP*256);
  for(int pi=0;pi<NP;pi++){
    float acc=0.f;
    #pragma unroll
    for(int i=0;i<16;i++) acc = fmaf(sn[pi*8+i], w[i], acc);
    xo[pi*256+tid] = f2u(acc);
  }
}

// ---------------- W_od = wo @ down_w (f32) ----------------
__global__ void __launch_bounds__(256) k_wod(const float* __restrict__ wo,
    const float* __restrict__ dw, float* __restrict__ wod)
{
  int i = blockIdx.x, blk = blockIdx.y, tid = threadIdx.x;
  __shared__ float row[512];
  const float* wr = wo + (blk*512 + i)*512;
  for(int k=tid;k<512;k+=256) row[k]=wr[k];
  __syncthreads();
  const float* d = dw + blk*512*256;
  float acc=0.f;
  for(int k=0;k<512;k++) acc = fmaf(row[k], d[k*256+tid], acc);
  wod[(blk*512+i)*256+tid]=acc;
}

// ---------------- transpose wod (512k x 256n) -> wodt bf16 [256][512] ----------------
__global__ void __launch_bounds__(256) k_tr_wodt(const float* __restrict__ wod, ushort* __restrict__ wodt)
{
  __shared__ float tile[32][33];
  int blk = blockIdx.z;
  int n0 = blockIdx.x*32, k0 = blockIdx.y*32;
  int tid = threadIdx.x;
  #pragma unroll
  for(int i=0;i<4;i++){
    int idx = tid + 256*i; int kl = idx>>5, nl = idx&31;
    tile[kl][nl] = wod[blk*512*256 + (k0+kl)*256 + n0+nl];
  }
  __syncthreads();
  #pragma unroll
  for(int i=0;i<4;i++){
    int idx = tid + 256*i; int nl = idx>>5, kl = idx&31;
    wodt[blk*256*512 + (n0+nl)*512 + k0+kl] = f2u(tile[kl][nl]);
  }
}

// ---------------- transpose [wi;wh] (768k x 2048n) -> wt bf16 [2048][768] ----------------
__global__ void __launch_bounds__(256) k_tr_lstmw(const float* __restrict__ wi,
    const float* __restrict__ wh, ushort* __restrict__ wt)
{
  __shared__ float tile[32][33];
  int blk = blockIdx.z;
  int n0 = blockIdx.x*32, k0 = blockIdx.y*32;
  int tid = threadIdx.x;
  #pragma unroll
  for(int i=0;i<4;i++){
    int idx = tid + 256*i; int kl = idx>>5, nl = idx&31;
    int k = k0+kl, n = n0+nl;
    float v = (k<256) ? wi[blk*256*2048 + k*2048 + n]
                      : wh[blk*512*2048 + (k-256)*2048 + n];
    tile[kl][nl] = v;
  }
  __syncthreads();
  #pragma unroll
  for(int i=0;i<4;i++){
    int idx = tid + 256*i; int nl = idx>>5, kl = idx&31;
    wt[blk*2048*768 + (n0+nl)*768 + k0+kl] = f2u(tile[kl][nl]);
  }
}

// ---------------- transpose [wq|wk|wv] (512k x 768n), fold ns[k] -> wqkvt bf16 [768][512] ----------------
__global__ void __launch_bounds__(256) k_tr_qkvw(const float* __restrict__ wq,
    const float* __restrict__ wk, const float* __restrict__ wv,
    const float* __restrict__ ns, ushort* __restrict__ wqkvt)
{
  __shared__ float tile[32][33];
  int blk = blockIdx.z;
  int n0 = blockIdx.x*32, k0 = blockIdx.y*32;
  int tid = threadIdx.x;
  #pragma unroll
  for(int i=0;i<4;i++){
    int idx = tid + 256*i; int kl = idx>>5, nl = idx&31;
    int k = k0+kl, n = n0+nl;
    float v;
    if(n < 512)      v = wq[blk*512*512 + k*512 + n];
    else if(n < 640) v = wk[blk*512*128 + k*128 + (n-512)];
    else             v = wv[blk*512*128 + k*128 + (n-640)];
    tile[kl][nl] = v * ns[blk*512 + k];
  }
  __syncthreads();
  #pragma unroll
  for(int i=0;i<4;i++){
    int idx = tid + 256*i; int nl = idx>>5, kl = idx&31;
    wqkvt[blk*768*512 + (n0+nl)*512 + k0+kl] = f2u(tile[kl][nl]);
  }
}

// ---------------- LSTM step via MFMA ----------------
// grid (16,16): block = 64 rows x 32 jj (x4 gates). 4 waves 2x2: wave = 32 rows x 16 jj x 4 gates.
__global__ void __launch_bounds__(256) k_lstm_m(
    const ushort* __restrict__ x, float* __restrict__ cst, ushort* __restrict__ hs,
    const ushort* __restrict__ wt, const float* __restrict__ bias, int t)
{
  __shared__ short As[64*40];   // 64 rows x 32 k, pad 40
  __shared__ short Bs[128*40];  // 128 n' (4g x 32jj) x 32 k, pad 40
  int tid = threadIdx.x;
  int n0 = blockIdx.x*64, jj0 = blockIdx.y*32;
  int wv = tid>>6, lane = tid&63, quad = lane>>4, l16 = lane&15;
  int wrow = wv>>1, wcol = wv&1;
  int arow = tid>>2, akp = tid&3;
  const ushort* aptr_x = x + ((n0+arow)*NP + t)*256 + akp*8;
  const ushort* aptr_h = hs + ((n0+arow)*NP + (t>0?t-1:0))*512 + akp*8;
  f32x4 acc[4][2];
  #pragma unroll
  for(int g=0;g<4;g++){
    #pragma unroll
    for(int a=0;a<2;a++) acc[g][a] = (f32x4){0.f,0.f,0.f,0.f};
  }
  const int K = (t==0)?256:768;
  for(int k0=0;k0<K;k0+=32){
    short8 av = (k0<256) ? *(const short8*)(aptr_x + k0)
                         : *(const short8*)(aptr_h + (k0-256));
    *(short8*)&As[arow*40 + akp*8] = av;
    #pragma unroll
    for(int i=0;i<2;i++){
      int p = tid + 256*i;
      int rl = p>>2, kp = p&3;
      int g = rl>>5, jjl = rl&31;
      short8 bv = *(const short8*)(wt + (g*512 + jj0 + jjl)*768 + k0 + kp*8);
      *(short8*)&Bs[rl*40 + kp*8] = bv;
    }
    __syncthreads();
    short8 af[2], bfr[4];
    #pragma unroll
    for(int a=0;a<2;a++) af[a] = *(short8*)&As[(wrow*32+a*16+l16)*40 + quad*8];
    #pragma unroll
    for(int g=0;g<4;g++) bfr[g] = *(short8*)&Bs[(g*32+wcol*16+l16)*40 + quad*8];
    #pragma unroll
    for(int g=0;g<4;g++){
      #pragma unroll
      for(int a=0;a<2;a++)
        acc[g][a] = __builtin_amdgcn_mfma_f32_16x16x32_bf16(af[a], bfr[g], acc[g][a], 0,0,0);
    }
    __syncthreads();
  }
  int jj = jj0 + wcol*16 + l16;
  float bI=bias[jj], bF=bias[512+jj], bG=bias[1024+jj], bO=bias[1536+jj];
  #pragma unroll
  for(int a=0;a<2;a++){
    #pragma unroll
    for(int r=0;r<4;r++){
      int n = n0 + wrow*32 + a*16 + quad*4 + r;
      float zi=acc[0][a][r]+bI, zf=acc[1][a][r]+bF, zg=acc[2][a][r]+bG, zo=acc[3][a][r]+bO;
      float cold = (t==0)?0.f:cst[n*512+jj];
      float c = sigf(zf)*cold + sigf(zi)*tanhf(zg);
      float hv = sigf(zo)*tanhf(c);
      cst[n*512+jj]=c;
      hs[(n*NP+t)*512+jj]=f2u(hv);
    }
  }
}

// ---------------- rms_inv over H2=512 for attention rows ----------------
__global__ void __launch_bounds__(256) k_rms(const ushort* __restrict__ hs, float* __restrict__ rmsi)
{
  int tid = threadIdx.x;
  int r = blockIdx.x*4 + (tid>>6);
  int lane = tid&63;
  int bq = r/8064; int rr = r - bq*8064;
  int m = rr/1008; int rem = rr - m*1008;
  int p = rem>>4; int d = rem&15;
  int n = (bq*16+d)*8+m;
  const ushort* hp = hs + (n*NP+p)*512;
  float s=0.f;
  for(int c=lane;c<512;c+=64){ float v=u2f(hp[c]); s += v*v; }
  #pragma unroll
  for(int off=32;off>0;off>>=1) s += __shfl_down(s,off);
  if(lane==0) rmsi[r] = rsqrtf(s*(1.f/512.f)+1e-6f);
}

// ---------------- qkv GEMM via MFMA: 64512 x 768, K=512; rms applied on output ----------------
// grid (1008, 6): block 64 rows x 128 cols, 4 waves split cols (64x32 each).
__global__ void __launch_bounds__(256) k_qkv_m(
    const ushort* __restrict__ hs, const float* __restrict__ rmsi,
    const ushort* __restrict__ wqkvt, ushort* __restrict__ qkv)
{
  __shared__ short As[64*40];
  __shared__ short Bs[128*40];
  int tid = threadIdx.x;
  int r0 = blockIdx.x*64, c0 = blockIdx.y*128;
  int wv = tid>>6, lane = tid&63, quad = lane>>4, l16 = lane&15;
  int arow = tid>>2, akp = tid&3;
  int r = r0 + arow;
  int bq = r/8064; int rr = r - bq*8064;
  int m = rr/1008; int rem = rr - m*1008;
  int p = rem>>4; int d = rem&15;
  int n = (bq*16+d)*8+m;
  const ushort* aptr = hs + (n*NP+p)*512 + akp*8;
  f32x4 acc[2][4];
  #pragma unroll
  for(int b=0;b<2;b++){
    #pragma unroll
    for(int a=0;a<4;a++) acc[b][a] = (f32x4){0.f,0.f,0.f,0.f};
  }
  for(int k0=0;k0<512;k0+=32){
    *(short8*)&As[arow*40+akp*8] = *(const short8*)(aptr + k0);
    #pragma unroll
    for(int i=0;i<2;i++){
      int pc = tid + 256*i; int rl=pc>>2, kp=pc&3;
      *(short8*)&Bs[rl*40+kp*8] = *(const short8*)(wqkvt + (c0+rl)*512 + k0 + kp*8);
    }
    __syncthreads();
    short8 af[4], bfr[2];
    #pragma unroll
    for(int a=0;a<4;a++) af[a] = *(short8*)&As[(a*16+l16)*40 + quad*8];
    #pragma unroll
    for(int b=0;b<2;b++) bfr[b] = *(short8*)&Bs[(wv*32+b*16+l16)*40 + quad*8];
    #pragma unroll
    for(int b=0;b<2;b++){
      #pragma unroll
      for(int a=0;a<4;a++)
        acc[b][a] = __builtin_amdgcn_mfma_f32_16x16x32_bf16(af[a], bfr[b], acc[b][a], 0,0,0);
    }
    __syncthreads();
  }
  #pragma unroll
  for(int a=0;a<4;a++){
    #pragma unroll
    for(int rg=0;rg<4;rg++){
      int rw = r0 + a*16 + quad*4 + rg;
      float rv = rmsi[rw];
      #pragma unroll
      for(int b=0;b<2;b++){
        int c = c0 + wv*32 + b*16 + l16;
        qkv[rw*768 + c] = f2u(acc[b][a][rg] * rv);
      }
    }
  }
}

// ---------------- attention (bf16 qkv buffer): per (row16-group, head) ----------------
__global__ void __launch_bounds__(256) k_attn(ushort* __restrict__ qkv)
{
  int r3 = blockIdx.x, h = blockIdx.y;
  int tid = threadIdx.x;
  __shared__ float qs[16][64];
  __shared__ float ks[16][65];
  __shared__ float vs[16][64];
  __shared__ float P[16][17];
  ushort* base = qkv + r3*16*768;
  int xx = tid&63, s4 = tid>>6;
  int kvh = (h>>2)*64;
  #pragma unroll
  for(int a=0;a<4;a++){
    int s = s4 + 4*a;
    qs[s][xx] = u2f(base[s*768 + h*64 + xx]);
    ks[s][xx] = u2f(base[s*768 + 512 + kvh + xx]);
    vs[s][xx] = u2f(base[s*768 + 640 + kvh + xx]);
  }
  __syncthreads();
  int i = tid>>4, j = tid&15;
  float sc = 0.f;
  #pragma unroll
  for(int x=0;x<64;x++) sc = fmaf(qs[i][x], ks[j][x], sc);
  P[i][j] = sc*0.125f;
  __syncthreads();
  float row[16];
  #pragma unroll
  for(int jj=0;jj<16;jj++) row[jj] = P[i][jj];
  float mx = row[0];
  #pragma unroll
  for(int jj=1;jj<16;jj++) mx = fmaxf(mx, row[jj]);
  float sum = 0.f;
  #pragma unroll
  for(int jj=0;jj<16;jj++) sum += expf(row[jj]-mx);
  float pme = expf(row[j]-mx)/sum;
  __syncthreads();
  P[i][j] = pme;
  __syncthreads();
  #pragma unroll
  for(int a=0;a<4;a++){
    int s = s4 + 4*a;
    float o = 0.f;
    #pragma unroll
    for(int jj=0;jj<16;jj++) o = fmaf(P[s][jj], vs[jj][xx], o);
    base[s*768 + h*64 + xx] = f2u(o);
  }
}

// ---------------- bel GEMM via MFMA: O(64512x512 in qkv) @ wodt^T -> scatter bf16 xbuf ----------------
// grid (1008, 2): block 64 x 128, waves split cols.
__global__ void __launch_bounds__(256) k_bel_m(
    const ushort* __restrict__ qkv, const ushort* __restrict__ wodt,
    ushort* __restrict__ x)
{
  __shared__ short As[64*40];
  __shared__ short Bs[128*40];
  int tid = threadIdx.x;
  int r0 = blockIdx.x*64, c0 = blockIdx.y*128;
  int wv = tid>>6, lane = tid&63, quad = lane>>4, l16 = lane&15;
  int arow = tid>>2, akp = tid&3;
  const ushort* aptr = qkv + (r0+arow)*768 + akp*8;
  f32x4 acc[2][4];
  #pragma unroll
  for(int b=0;b<2;b++){
    #pragma unroll
    for(int a=0;a<4;a++) acc[b][a] = (f32x4){0.f,0.f,0.f,0.f};
  }
  for(int k0=0;k0<512;k0+=32){
    *(short8*)&As[arow*40+akp*8] = *(const short8*)(aptr + k0);
    #pragma unroll
    for(int i=0;i<2;i++){
      int pc = tid + 256*i; int rl=pc>>2, kp=pc&3;
      *(short8*)&Bs[rl*40+kp*8] = *(const short8*)(wodt + (c0+rl)*512 + k0 + kp*8);
    }
    __syncthreads();
    short8 af[4], bfr[2];
    #pragma unroll
    for(int a=0;a<4;a++) af[a] = *(short8*)&As[(a*16+l16)*40 + quad*8];
    #pragma unroll
    for(int b=0;b<2;b++) bfr[b] = *(short8*)&Bs[(wv*32+b*16+l16)*40 + quad*8];
    #pragma unroll
    for(int b=0;b<2;b++){
      #pragma unroll
      for(int a=0;a<4;a++)
        acc[b][a] = __builtin_amdgcn_mfma_f32_16x16x32_bf16(af[a], bfr[b], acc[b][a], 0,0,0);
    }
    __syncthreads();
  }
  #pragma unroll
  for(int a=0;a<4;a++){
    #pragma unroll
    for(int rg=0;rg<4;rg++){
      int rw = r0 + a*16 + quad*4 + rg;
      int bq = rw/8064; int rr = rw - bq*8064;
      int m = rr/1008; int rem = rr - m*1008;
      int p = rem>>4; int d = rem&15;
      int n = (bq*16+d)*8+m;
      ushort* xo = x + (n*NP+p)*256;
      #pragma unroll
      for(int b=0;b<2;b++){
        int c = c0 + wv*32 + b*16 + l16;
        xo[c] = f2u(acc[b][a][rg]);
      }
    }
  }
}

// ---------------- head ----------------
__global__ void __launch_bounds__(256) k_head(const ushort* __restrict__ x,
    const float* __restrict__ meanv, const float* __restrict__ stdv,
    const float* __restrict__ rs, const float* __restrict__ rb,
    const float* __restrict__ hns, const float* __restrict__ pw,
    const float* __restrict__ qw, float* __restrict__ out)
{
  int n = blockIdx.x, tid = threadIdx.x;
  __shared__ float nb[256];
  __shared__ float red[256];
  float v = u2f(x[(n*NP + 62)*256 + tid]);
  red[tid] = v*v; __syncthreads();
  for(int s=128;s>0;s>>=1){
    if(tid<s) red[tid]+=red[tid+s];
    __syncthreads();
  }
  float rinv = rsqrtf(red[0]*(1.f/256.f)+1e-6f);
  nb[tid] = v*rinv*hns[tid];
  __syncthreads();
  int m = n&7;
  float mu=meanv[n], sd=stdv[n], sc=rs[m], bi=rb[m];
  for(int col=tid; col<384; col+=256){
    float acc=0.f;
    int slot, hh;
    if(col < 96){
      for(int k=0;k<256;k++) acc = fmaf(nb[k], pw[k*96+col], acc);
      slot = 0; hh = col;
    } else {
      int cq = col-96;
      for(int k=0;k<256;k++) acc = fmaf(nb[k], qw[k*288+cq], acc);
      int qi = cq - (cq/3)*3;
      slot = 1 + qi; hh = cq/3;
    }
    float y = (acc - bi)/sc*sd + mu;
    out[(slot*1024 + n)*96 + hh] = y;
  }
}

extern "C" void kernel_launch(void* const* d_in, const int* in_sizes, int n_in,
                              void* d_out, int out_size, void* d_ws, size_t ws_size,
                              hipStream_t stream)
{
  const float* series    = (const float*)d_in[0];
  const float* rs        = (const float*)d_in[1];
  const float* rb        = (const float*)d_in[2];
  const float* up_w      = (const float*)d_in[3];
  const float* lstm_wi   = (const float*)d_in[4];
  const float* lstm_wh   = (const float*)d_in[5];
  const float* lstm_b    = (const float*)d_in[6];
  const float* norm_scale= (const float*)d_in[7];
  const float* wq        = (const float*)d_in[8];
  const float* wk        = (const float*)d_in[9];
  const float* wv        = (const float*)d_in[10];
  const float* wo        = (const float*)d_in[11];
  const float* down_w    = (const float*)d_in[12];
  const float* head_ns   = (const float*)d_in[13];
  const float* point_w   = (const float*)d_in[14];
  const float* quant_w   = (const float*)d_in[15];
  float* out = (float*)d_out;

  float* ws = (float*)d_ws;
  float*  meanv = ws;                       // 1024
  float*  stdv  = meanv + 1024;             // 1024
  float*  rmsi  = stdv  + 1024;             // 64512
  float*  cst   = rmsi  + 64512;            // 524288
  float*  wodf  = cst   + 524288;           // 524288
  ushort* xbuf  = (ushort*)(wodf + 524288);         // 16515072 bf16
  ushort* hsb   = xbuf  + 16515072;                 // 33030144 bf16
  ushort* qkvb  = hsb   + 33030144;                 // 49545216 bf16
  ushort* wt    = qkvb  + 49545216;                 // 6291456 bf16
  ushort* wqkvt = wt    + 6291456;                  // 1572864 bf16
  ushort* wodt  = wqkvt + 1572864;                  // 524288 bf16
  // total ~219.4 MB

  k_revin<<<1024,256,0,stream>>>(series, meanv, stdv);
  k_patch<<<1024,256,0,stream>>>(series, rs, rb, up_w, meanv, stdv, xbuf);
  k_wod<<<dim3(512,4),256,0,stream>>>(wo, down_w, wodf);
  k_tr_wodt<<<dim3(8,16,4),256,0,stream>>>(wodf, wodt);
  k_tr_lstmw<<<dim3(64,24,4),256,0,stream>>>(lstm_wi, lstm_wh, wt);
  k_tr_qkvw<<<dim3(24,16,4),256,0,stream>>>(wq, wk, wv, norm_scale, wqkvt);

  for(int blk=0; blk<4; blk++){
    const ushort* wt_b = wt + blk*2048*768;
    const float*  bb   = lstm_b + blk*2048;
    for(int t=0; t<NP; t++)
      k_lstm_m<<<dim3(16,16),256,0,stream>>>(xbuf, cst, hsb, wt_b, bb, t);
    k_rms<<<16128,256,0,stream>>>(hsb, rmsi);
    k_qkv_m<<<dim3(1008,6),256,0,stream>>>(hsb, rmsi, wqkvt + blk*768*512, qkvb);
    k_attn<<<dim3(4032,8),256,0,stream>>>(qkvb);
    k_bel_m<<<dim3(1008,2),256,0,stream>>>(qkvb, wodt + blk*256*512, xbuf);
  }
  k_head<<<1024,256,0,stream>>>(xbuf, meanv, stdv, rs, rb, head_ns, point_w, quant_w, out);
}